// Round 1
// baseline (1201.645 us; speedup 1.0000x reference)
//
#include <hip/hip_runtime.h>

// QPooling, D=64, K=2, ND=32, B=16.
// out[b, X=(p*32+q), Y=(r*32+s)] = gather of up to 4 rho elements (see analysis).
// rho: (16, 4096, 4096) f32; out: (16, 1024, 1024) f32. Pure gather, no atomics.

#define D 64
#define DD 4096          // D*D
#define ND 32
#define ND2 1024         // ND*ND
#define BATCH 16

__global__ __launch_bounds__(256) void qpool_gather(const float* __restrict__ rho,
                                                    float* __restrict__ out) {
    int tid = blockIdx.x * blockDim.x + threadIdx.x;  // 0 .. 16*1024*1024-1
    int Y = tid & (ND2 - 1);
    int X = (tid >> 10) & (ND2 - 1);
    int b = tid >> 20;

    int s = Y & (ND - 1);
    int r = Y >> 5;
    int q = X & (ND - 1);
    int p = X >> 5;

    const float* base = rho + (size_t)b * DD * DD;

    // term 1: x=(2p,2q), y=(2r,2s)  -- always
    int row0 = (p << 7) + (q << 1);          // 2p*64 + 2q
    int col0 = (r << 7) + (s << 1);          // 2r*64 + 2s
    float v = base[(size_t)row0 * DD + col0];

    // term 2: x=(2p,2q+1), y=(2r,2q+1)  -- iff s==q
    if (s == q) {
        int row1 = row0 + 1;                 // 2p*64 + 2q + 1
        int col1 = (r << 7) + (q << 1) + 1;  // 2r*64 + 2q + 1
        v += base[(size_t)row1 * DD + col1];
    }

    // term 3: x=(2p+1,2q), y=(2p+1,2s)  -- iff r==p
    if (r == p) {
        int row2 = (p << 7) + D + (q << 1);  // (2p+1)*64 + 2q
        int col2 = (p << 7) + D + (s << 1);  // (2p+1)*64 + 2s
        v += base[(size_t)row2 * DD + col2];

        // term 4: x=y=(2p+1,2q+1)  -- iff r==p && s==q
        if (s == q) {
            int rc = (p << 7) + D + (q << 1) + 1;  // (2p+1)*64 + 2q+1
            v += base[(size_t)rc * DD + rc];
        }
    }

    out[tid] = v;
}

extern "C" void kernel_launch(void* const* d_in, const int* in_sizes, int n_in,
                              void* d_out, int out_size, void* d_ws, size_t ws_size,
                              hipStream_t stream) {
    const float* rho = (const float*)d_in[0];
    float* out = (float*)d_out;
    // out_size = 16 * 1024 * 1024
    int total = BATCH * ND2 * ND2;
    int block = 256;
    int grid = total / block;  // 65536
    qpool_gather<<<grid, block, 0, stream>>>(rho, out);
}